// Round 1
// baseline (153.735 us; speedup 1.0000x reference)
//
#include <hip/hip_runtime.h>
#include <math.h>

// Problem constants (fixed by reference setup_inputs)
constexpr int Bv = 8;
constexpr int Sv = 4096;
constexpr int Dv = 512;
constexpr int NCv = 64;           // S-chunks for pass-1 partials
constexpr int SCv = Sv / NCv;     // 64 rows per chunk
constexpr int Pv = 98;            // sampled partitions
constexpr int Kv = 6;             // max parts per partition
constexpr int MAXPv = 100;

// Workspace layout (float offsets)
constexpr size_t OFF_MPART = 0;
constexpr size_t OFF_ZPART = OFF_MPART + (size_t)Bv * NCv * Dv;
constexpr size_t OFF_TPART = OFF_ZPART + (size_t)Bv * NCv * Dv;
constexpr size_t OFF_XMAX  = OFF_TPART + (size_t)Bv * NCv * Dv;
constexpr size_t OFF_ED    = OFF_XMAX + (size_t)Bv * Dv;
constexpr size_t OFF_TD    = OFF_ED   + (size_t)Bv * Dv;
constexpr size_t OFF_HFULL = OFF_TD   + (size_t)Bv * Dv;   // [B]
constexpr size_t OFF_HSD   = OFF_HFULL + Bv;               // [B] sum_d H_sd
constexpr size_t OFF_HBP   = OFF_HSD + Bv;                 // [B*P] sum_k H_pk
constexpr size_t OFF_ASSIGN = OFF_HBP + (size_t)Bv * Pv;   // bytes from here: [P*D] uint8

__device__ __forceinline__ float warpSum(float v) {
    for (int o = 32; o > 0; o >>= 1) v += __shfl_xor(v, o);
    return v;
}
__device__ __forceinline__ float warpMax(float v) {
    for (int o = 32; o > 0; o >>= 1) v = fmaxf(v, __shfl_xor(v, o));
    return v;
}
// 512-thread block reductions; `red` is shared float[8]; returns value to ALL threads.
__device__ __forceinline__ float blockSum512(float v, float* red) {
    float s = warpSum(v);
    int lane = threadIdx.x & 63, w = threadIdx.x >> 6;
    __syncthreads();
    if (lane == 0) red[w] = s;
    __syncthreads();
    return red[0] + red[1] + red[2] + red[3] + red[4] + red[5] + red[6] + red[7];
}
__device__ __forceinline__ float blockMax512(float v, float* red) {
    float s = warpMax(v);
    int lane = threadIdx.x & 63, w = threadIdx.x >> 6;
    __syncthreads();
    if (lane == 0) red[w] = s;
    __syncthreads();
    float m = red[0];
    for (int i = 1; i < 8; i++) m = fmaxf(m, red[i]);
    return m;
}

// Order-preserving float<->uint encoding (for LDS atomicMax on floats)
__device__ __forceinline__ unsigned int encf(float f) {
    unsigned int u = __float_as_uint(f);
    return (u & 0x80000000u) ? ~u : (u | 0x80000000u);
}
__device__ __forceinline__ float decf(unsigned int u) {
    return (u & 0x80000000u) ? __uint_as_float(u ^ 0x80000000u) : __uint_as_float(~u);
}

// Online softmax-stat update: (m, z, t) += element v
#define UPD(v, m, z, t)                                        \
    {                                                          \
        float vv = (v);                                        \
        if (vv > m) {                                          \
            float r = __expf(m - vv);                          \
            z = z * r + 1.0f;                                  \
            t = t * r + vv;                                    \
            m = vv;                                            \
        } else {                                               \
            float e_ = __expf(vv - m);                         \
            z += e_;                                           \
            t += e_ * vv;                                      \
        }                                                      \
    }

// Merge two stat triples: (m,z,t) <- merge((m,z,t),(mb,zb,tb)). Safe when m==-inf.
__device__ __forceinline__ void mergeStats(float& m, float& z, float& t,
                                           float mb, float zb, float tb) {
    float nm = fmaxf(m, mb);
    float ra = __expf(m - nm);
    float rb = __expf(mb - nm);
    z = z * ra + zb * rb;
    t = t * ra + tb * rb;
    m = nm;
}

// ---------------------------------------------------------------------------
// Kernel A: build per-(p,d) part assignment from part_masks.
// Mask storage ambiguity (bool bytes vs int32) is self-detected per block:
// scan first 1024 uint32 words; uint8-packed bools yield words > 1.
// ---------------------------------------------------------------------------
__global__ __launch_bounds__(512) void k_assign(const void* __restrict__ masks,
                                                float* __restrict__ ws) {
    int p = blockIdx.x;
    int d = threadIdx.x;
    __shared__ int f;
    if (d == 0) f = 0;
    __syncthreads();
    const unsigned int* mw = (const unsigned int*)masks;
    if (mw[d] > 1u || mw[d + 512] > 1u) atomicOr(&f, 1);
    __syncthreads();
    int is_u8 = f;

    unsigned char a = 255;
    if (is_u8) {
        const unsigned char* mb = (const unsigned char*)masks;
        for (int k = 0; k < Kv; k++) {
            if (mb[((size_t)p * Kv + k) * Dv + d]) { a = (unsigned char)k; break; }
        }
    } else {
        const int* mi = (const int*)masks;
        for (int k = 0; k < Kv; k++) {
            if (mi[((size_t)p * Kv + k) * Dv + d]) { a = (unsigned char)k; break; }
        }
    }
    ((unsigned char*)(ws + OFF_ASSIGN))[(size_t)p * Dv + d] = a;
}

// ---------------------------------------------------------------------------
// Kernel 1: pass over x, per-(b, chunk, d) online stats (m, Z, T).
// Block = 256 threads: tid&127 -> d-group (4 consecutive d via float4),
// tid>>7 -> s interleave (2 sub-accumulators merged in LDS).
// ---------------------------------------------------------------------------
__global__ __launch_bounds__(256) void k1_partial(const float* __restrict__ x,
                                                  float* __restrict__ ws) {
    int c = blockIdx.x;
    int b = blockIdx.y;
    int tid = threadIdx.x;
    int dg = tid & 127;
    int sl = tid >> 7;

    const float4* xv = (const float4*)x;
    float m0 = -INFINITY, m1 = -INFINITY, m2 = -INFINITY, m3 = -INFINITY;
    float z0 = 0.f, z1 = 0.f, z2 = 0.f, z3 = 0.f;
    float t0 = 0.f, t1 = 0.f, t2 = 0.f, t3 = 0.f;

    int sbase = c * SCv + sl;
    for (int i = 0; i < SCv / 2; i++) {
        int s = sbase + 2 * i;
        float4 v = xv[((size_t)b * Sv + s) * 128 + dg];
        UPD(v.x, m0, z0, t0);
        UPD(v.y, m1, z1, t1);
        UPD(v.z, m2, z2, t2);
        UPD(v.w, m3, z3, t3);
    }

    // merge the two s-interleaves via LDS
    __shared__ float smm[128 * 4], smz[128 * 4], smt[128 * 4];
    if (sl == 1) {
        smm[dg * 4 + 0] = m0; smm[dg * 4 + 1] = m1; smm[dg * 4 + 2] = m2; smm[dg * 4 + 3] = m3;
        smz[dg * 4 + 0] = z0; smz[dg * 4 + 1] = z1; smz[dg * 4 + 2] = z2; smz[dg * 4 + 3] = z3;
        smt[dg * 4 + 0] = t0; smt[dg * 4 + 1] = t1; smt[dg * 4 + 2] = t2; smt[dg * 4 + 3] = t3;
    }
    __syncthreads();
    if (sl == 0) {
        mergeStats(m0, z0, t0, smm[dg * 4 + 0], smz[dg * 4 + 0], smt[dg * 4 + 0]);
        mergeStats(m1, z1, t1, smm[dg * 4 + 1], smz[dg * 4 + 1], smt[dg * 4 + 1]);
        mergeStats(m2, z2, t2, smm[dg * 4 + 2], smz[dg * 4 + 2], smt[dg * 4 + 2]);
        mergeStats(m3, z3, t3, smm[dg * 4 + 3], smz[dg * 4 + 3], smt[dg * 4 + 3]);

        size_t o = ((size_t)(b * NCv + c)) * 128 + dg;   // float4 index into [.,D]
        ((float4*)(ws + OFF_MPART))[o] = make_float4(m0, m1, m2, m3);
        ((float4*)(ws + OFF_ZPART))[o] = make_float4(z0, z1, z2, z3);
        ((float4*)(ws + OFF_TPART))[o] = make_float4(t0, t1, t2, t3);
    }
}

// ---------------------------------------------------------------------------
// Kernel 2: combine chunk partials per (b,d); emit xmax/e/t arrays, per-b
// H_sd sum, and per-b full-flatten entropy.
// ---------------------------------------------------------------------------
__global__ __launch_bounds__(512) void k2_combine(float* __restrict__ ws) {
    int b = blockIdx.x;
    int d = threadIdx.x;
    const float* mp = ws + OFF_MPART;
    const float* zp = ws + OFF_ZPART;
    const float* tp = ws + OFF_TPART;

    float m = -INFINITY, z = 0.f, t = 0.f;
    for (int c = 0; c < NCv; c++) {
        size_t idx = ((size_t)(b * NCv + c)) * Dv + d;
        mergeStats(m, z, t, mp[idx], zp[idx], tp[idx]);
    }

    ws[OFF_XMAX + (size_t)b * Dv + d] = m;
    ws[OFF_ED   + (size_t)b * Dv + d] = z;
    ws[OFF_TD   + (size_t)b * Dv + d] = t;

    float hsd = m + __logf(z) - t / z;   // per-(b,d) seq entropy

    __shared__ float red[8];
    float sum_h = blockSum512(hsd, red);
    float mb = blockMax512(m, red);
    float sc = __expf(m - mb);
    float zb = blockSum512(z * sc, red);
    float tb = blockSum512(t * sc, red);
    if (d == 0) {
        ws[OFF_HSD + b] = sum_h;
        ws[OFF_HFULL + b] = mb + __logf(zb) - tb / zb;
    }
}

// ---------------------------------------------------------------------------
// Kernel 3: sampled partitions. One block per (p,b); group max via encoded
// LDS atomicMax, then Z/T via LDS float atomicAdd; write sum_k H_pk.
// ---------------------------------------------------------------------------
__global__ __launch_bounds__(512) void k3_parts(float* __restrict__ ws) {
    int p = blockIdx.x;
    int b = blockIdx.y;
    int d = threadIdx.x;

    float xm = ws[OFF_XMAX + (size_t)b * Dv + d];
    float e  = ws[OFF_ED   + (size_t)b * Dv + d];
    float t  = ws[OFF_TD   + (size_t)b * Dv + d];
    int k = ((const unsigned char*)(ws + OFF_ASSIGN))[(size_t)p * Dv + d];

    __shared__ unsigned int gmu[Kv];
    __shared__ float sz[Kv], st[Kv], hk[Kv];
    const unsigned int ENC_NEGINF = 0x007FFFFFu;   // encf(-inf)
    if (d < Kv) { gmu[d] = ENC_NEGINF; sz[d] = 0.f; st[d] = 0.f; }
    __syncthreads();
    if (k < Kv) atomicMax(&gmu[k], encf(xm));
    __syncthreads();
    if (k < Kv) {
        float g = decf(gmu[k]);
        float s = __expf(xm - g);
        atomicAdd(&sz[k], e * s);
        atomicAdd(&st[k], t * s);
    }
    __syncthreads();
    if (d < Kv) {
        float h = 0.f;
        unsigned int u = gmu[d];
        if (u != ENC_NEGINF) {
            float Z = sz[d];
            h = decf(u) + __logf(Z) - st[d] / Z;
        }
        hk[d] = h;
    }
    __syncthreads();
    if (d == 0)
        ws[OFF_HBP + (size_t)b * Pv + p] = hk[0] + hk[1] + hk[2] + hk[3] + hk[4] + hk[5];
}

// ---------------------------------------------------------------------------
// Kernel 4: combine 100 partition entropies, weighted min, MLP head.
// ---------------------------------------------------------------------------
__device__ __forceinline__ float sigmoidf(float v) { return 1.0f / (1.0f + __expf(-v)); }

__global__ __launch_bounds__(128) void k4_final(
    const float* __restrict__ es, const float* __restrict__ iw,
    const float* __restrict__ W1, const float* __restrict__ b1,
    const float* __restrict__ W2, const float* __restrict__ b2,
    const float* __restrict__ W3, const float* __restrict__ b3,
    const float* __restrict__ ws, float* __restrict__ out) {
    int tid = threadIdx.x;
    __shared__ float wgt[MAXPv];
    __shared__ float meanH_s;
    __shared__ float red[2];

    // mean(entropy_scales) over 512 elems
    float v = es[tid] + es[tid + 128] + es[tid + 256] + es[tid + 384];
    float s64 = warpSum(v);
    int lane = tid & 63, w = tid >> 6;
    if (lane == 0) red[w] = s64;
    __syncthreads();
    float es_mean = (red[0] + red[1]) * (1.0f / 512.0f);

    if (tid < Pv) {
        float s = 0.f;
        for (int b = 0; b < Bv; b++) s += ws[OFF_HBP + (size_t)b * Pv + tid];
        wgt[tid + 2] = (s * (1.0f / Bv)) * sigmoidf(iw[tid + 2]);
    } else if (tid == Pv) {          // h_whole
        float s = 0.f;
        for (int b = 0; b < Bv; b++) s += ws[OFF_HFULL + b];
        float mh = s * (1.0f / Bv);
        meanH_s = mh;
        wgt[0] = mh * sigmoidf(iw[0]);
    } else if (tid == Pv + 1) {      // h_single
        float s = 0.f;
        for (int b = 0; b < Bv; b++) s += ws[OFF_HSD + b];
        wgt[1] = (s * (1.0f / Bv)) * sigmoidf(iw[1]);
    }
    __syncthreads();

    if (tid == 0) {
        float mn = wgt[0];
        for (int i = 1; i < MAXPv; i++) mn = fminf(mn, wgt[i]);
        float raw = es_mean * meanH_s - mn;
        float z = fminf(fmaxf(raw * 0.1f, 0.0f), 1.0f);

        float h1[32];
        for (int j = 0; j < 32; j++) {
            float a = z * W1[j] + b1[j];
            h1[j] = a > 0.f ? a : 0.f;
        }
        float h2[16];
        for (int i = 0; i < 16; i++) {
            float a = b2[i];
            for (int j = 0; j < 32; j++) a += W2[i * 32 + j] * h1[j];
            h2[i] = a > 0.f ? a : 0.f;
        }
        float a = b3[0];
        for (int i = 0; i < 16; i++) a += W3[i] * h2[i];
        out[0] = sigmoidf(a);
    }
}

extern "C" void kernel_launch(void* const* d_in, const int* in_sizes, int n_in,
                              void* d_out, int out_size, void* d_ws, size_t ws_size,
                              hipStream_t stream) {
    const float* x  = (const float*)d_in[0];
    const float* es = (const float*)d_in[1];
    const float* iw = (const float*)d_in[2];
    const float* W1 = (const float*)d_in[3];
    const float* b1 = (const float*)d_in[4];
    const float* W2 = (const float*)d_in[5];
    const float* b2 = (const float*)d_in[6];
    const float* W3 = (const float*)d_in[7];
    const float* b3 = (const float*)d_in[8];
    const void* masks = d_in[9];
    float* ws = (float*)d_ws;
    float* out = (float*)d_out;

    k_assign<<<dim3(Pv), dim3(512), 0, stream>>>(masks, ws);
    k1_partial<<<dim3(NCv, Bv), dim3(256), 0, stream>>>(x, ws);
    k2_combine<<<dim3(Bv), dim3(512), 0, stream>>>(ws);
    k3_parts<<<dim3(Pv, Bv), dim3(512), 0, stream>>>(ws);
    k4_final<<<dim3(1), dim3(128), 0, stream>>>(es, iw, W1, b1, W2, b2, W3, b3, ws, out);
}